// Round 5
// baseline (296.168 us; speedup 1.0000x reference)
//
#include <hip/hip_runtime.h>
#include <hip/hip_bf16.h>

// InfoNCE: a[4096,512], p[4096,512], n[16384,512] f32 -> 4 f32 scalars.
// R5: software-pipelined fp8 GEMM. BKB=64-byte K-chunks, double-buffered LDS
//     (2x(8+8) KB = 32 KB, unchanged), loads for chunk it+1 issue BEFORE the
//     compute of chunk it, ONE barrier per iteration. Fully unrolled (8 iters),
//     ds_read offsets loop-invariant. Breaks the stage->drain->compute convoy
//     (R4 pipes summed serially: 26 MFMA + 20 LDS + 16 stage + 20 VALU = 82us).
// ws layout: a8(2MB) p8(2MB) n8(8MB) | S[4096] csA[512*16] csP[512*16] csN[512*16] lsum[1]

#define D_DIM 512
#define B_ROWS 4096
#define P_ROWS 4096
#define N_ROWS 16384
#define INV_T 14.285714285714286f
#define EPS_L 1e-8f
#define CS_STRIDE 16

typedef unsigned char fp8_t;
typedef __attribute__((ext_vector_type(4))) float floatx4;   // MFMA C/D frag
typedef __attribute__((ext_vector_type(2))) long longx2;     // 16B LDS read = 2 MFMA operands
typedef unsigned int uint32;

// ---- fused: L2-normalize rows -> fp8 e4m3, and accumulate fp32 column sums ----
__global__ __launch_bounds__(256) void norm_colsum(
        const float* __restrict__ a, const float* __restrict__ p, const float* __restrict__ n,
        fp8_t* __restrict__ a8, fp8_t* __restrict__ p8, fp8_t* __restrict__ n8,
        float* __restrict__ csA, float* __restrict__ csP, float* __restrict__ csN) {
    const float* in; fp8_t* outp; float* cs; int rows, nb, bseg;
    int b = blockIdx.x;
    if (b < 256)      { in = a; outp = a8; cs = csA; rows = B_ROWS; nb = 256; bseg = b; }
    else if (b < 512) { in = p; outp = p8; cs = csP; rows = P_ROWS; nb = 256; bseg = b - 256; }
    else              { in = n; outp = n8; cs = csN; rows = N_ROWS; nb = 512; bseg = b - 512; }

    const int wave = threadIdx.x >> 6;
    const int lane = threadIdx.x & 63;

    float cs0[4] = {0.f, 0.f, 0.f, 0.f};
    float cs1[4] = {0.f, 0.f, 0.f, 0.f};

    for (int chunk = bseg; chunk < (rows >> 2); chunk += nb) {
        int r = chunk * 4 + wave;
        const float4* rp = reinterpret_cast<const float4*>(in + (size_t)r * D_DIM);
        float4 v0 = rp[lane];
        float4 v1 = rp[lane + 64];
        float ss = v0.x*v0.x + v0.y*v0.y + v0.z*v0.z + v0.w*v0.w
                 + v1.x*v1.x + v1.y*v1.y + v1.z*v1.z + v1.w*v1.w;
#pragma unroll
        for (int off = 1; off < 64; off <<= 1) ss += __shfl_xor(ss, off);
        float inv = 1.0f / fmaxf(sqrtf(ss), 1e-12f);
        float f0x = v0.x*inv, f0y = v0.y*inv, f0z = v0.z*inv, f0w = v0.w*inv;
        float f1x = v1.x*inv, f1y = v1.y*inv, f1z = v1.z*inv, f1w = v1.w*inv;
        cs0[0] += f0x; cs0[1] += f0y; cs0[2] += f0z; cs0[3] += f0w;
        cs1[0] += f1x; cs1[1] += f1y; cs1[2] += f1z; cs1[3] += f1w;
        int pk0 = __builtin_amdgcn_cvt_pk_fp8_f32(f0x, f0y, 0, 0);
        pk0     = __builtin_amdgcn_cvt_pk_fp8_f32(f0z, f0w, pk0, 1);
        int pk1 = __builtin_amdgcn_cvt_pk_fp8_f32(f1x, f1y, 0, 0);
        pk1     = __builtin_amdgcn_cvt_pk_fp8_f32(f1z, f1w, pk1, 1);
        uint32* op = reinterpret_cast<uint32*>(outp + (size_t)r * D_DIM);
        op[lane]      = (uint32)pk0;
        op[lane + 64] = (uint32)pk1;
    }

    __shared__ float csh[D_DIM];
    if (threadIdx.x < 256) { csh[threadIdx.x] = 0.f; csh[threadIdx.x + 256] = 0.f; }
    __syncthreads();
#pragma unroll
    for (int j = 0; j < 4; ++j) {
        atomicAdd(&csh[lane * 4 + j], cs0[j]);
        atomicAdd(&csh[256 + lane * 4 + j], cs1[j]);
    }
    __syncthreads();
    if (threadIdx.x < 256) {
        atomicAdd(&cs[(size_t)threadIdx.x * CS_STRIDE], csh[threadIdx.x]);
        atomicAdd(&cs[(size_t)(threadIdx.x + 256) * CS_STRIDE], csh[threadIdx.x + 256]);
    }
}

// ---------------- fp8 MFMA GEMM, software-pipelined ----------------
#define BM 128
#define BN 128
#define BKB 64               // bytes (=fp8 elems) per K-chunk per row
#define NCHUNK (D_DIM / BKB) // 8

typedef const __attribute__((address_space(1))) unsigned int* as1_u32p;
typedef __attribute__((address_space(3))) unsigned int* as3_u32p;

__device__ __forceinline__ void load_lds16(const void* g, void* l) {
    __builtin_amdgcn_global_load_lds((as1_u32p)g, (as3_u32p)l, 16, 0, 0);
}

// EPI==0: C = A@Bm^T, S[row] += sum_col exp(C*invT)           (neg pass)
// EPI==1: loss_sum += sum(-log(exp(C*invT)/(exp+S[row])+eps)) (pos pass)
template <int EPI>
__global__ __launch_bounds__(256, 4) void gemm_epi(const fp8_t* __restrict__ A,
                                                   const fp8_t* __restrict__ Bm,
                                                   float* __restrict__ S,
                                                   float* __restrict__ loss_sum) {
    // double-buffered 8 KB chunk tiles (128 rows x 64 B), XOR-swizzled granules
    __shared__ fp8_t As[2][BM * BKB];
    __shared__ fp8_t Bs[2][BN * BKB];

    const int tid  = threadIdx.x;
    const int lane = tid & 63;
    const int w    = tid >> 6;
    const int wm   = w >> 1, wn = w & 1;
    const int m0   = blockIdx.y * BM;
    const int n0   = blockIdx.x * BN;
    const int lr   = lane & 15;
    const int q    = lane >> 4;

    floatx4 acc[4][4];
#pragma unroll
    for (int i = 0; i < 4; ++i)
#pragma unroll
        for (int j = 0; j < 4; ++j) acc[i][j] = (floatx4){0.f, 0.f, 0.f, 0.f};

    // ---- staging geometry: one load_lds instr = 16 rows x 64 B = 1 KB ----
    // lane -> row srow = lane>>2, granule sg = (lane&3) ^ (srow&3)  (XOR swizzle
    // folded into gather; LDS dest is lane-contiguous).
    const int srow = lane >> 2;             // 0..15
    const int sg   = (lane & 3) ^ (srow & 3);
    // wave w stages rows [w*32, w*32+32) of both tiles (2 instrs each)
    const fp8_t* gA0 = A + (size_t)(m0 + w * 32 + srow) * D_DIM + sg * 16;
    const fp8_t* gA1 = gA0 + 16 * D_DIM;
    const fp8_t* gB0 = Bm + (size_t)(n0 + w * 32 + srow) * D_DIM + sg * 16;
    const fp8_t* gB1 = gB0 + 16 * D_DIM;
    const int dst0 = (w * 32) * BKB;        // byte offset of 1st 1KB dest
    const int dst1 = (w * 32 + 16) * BKB;

    // ---- ds_read offsets (loop-invariant): lane reads granule q of row r,
    // stored at slot q^(r&3); r&3 == lr&3 ----
    int aoff[4], boff[4];
#pragma unroll
    for (int rt = 0; rt < 4; ++rt) {
        int r = wm * 64 + rt * 16 + lr;
        aoff[rt] = r * BKB + ((q ^ (lr & 3)) << 4);
    }
#pragma unroll
    for (int ct = 0; ct < 4; ++ct) {
        int r = wn * 64 + ct * 16 + lr;
        boff[ct] = r * BKB + ((q ^ (lr & 3)) << 4);
    }

    // prologue: stage chunk 0 into buffer 0
    load_lds16(gA0, &As[0][dst0]);
    load_lds16(gA1, &As[0][dst1]);
    load_lds16(gB0, &Bs[0][dst0]);
    load_lds16(gB1, &Bs[0][dst1]);
    __syncthreads();

#pragma unroll
    for (int it = 0; it < NCHUNK; ++it) {
        const int cur = it & 1;
        // issue next chunk's loads into the other buffer (in flight during compute)
        if (it + 1 < NCHUNK) {
            const int nxt = cur ^ 1;
            const int c   = (it + 1) * BKB;
            load_lds16(gA0 + c, &As[nxt][dst0]);
            load_lds16(gA1 + c, &As[nxt][dst1]);
            load_lds16(gB0 + c, &Bs[nxt][dst0]);
            load_lds16(gB1 + c, &Bs[nxt][dst1]);
        }
        // compute current chunk: 8 ds_read_b128 + 32 MFMA
        longx2 av[4], bv[4];
#pragma unroll
        for (int rt = 0; rt < 4; ++rt) av[rt] = *reinterpret_cast<const longx2*>(&As[cur][aoff[rt]]);
#pragma unroll
        for (int ct = 0; ct < 4; ++ct) bv[ct] = *reinterpret_cast<const longx2*>(&Bs[cur][boff[ct]]);
#pragma unroll
        for (int rt = 0; rt < 4; ++rt)
#pragma unroll
            for (int ct = 0; ct < 4; ++ct)
                acc[rt][ct] = __builtin_amdgcn_mfma_f32_16x16x32_fp8_fp8(av[rt].x, bv[ct].x,
                                                                         acc[rt][ct], 0, 0, 0);
#pragma unroll
        for (int rt = 0; rt < 4; ++rt)
#pragma unroll
            for (int ct = 0; ct < 4; ++ct)
                acc[rt][ct] = __builtin_amdgcn_mfma_f32_16x16x32_fp8_fp8(av[rt].y, bv[ct].y,
                                                                         acc[rt][ct], 0, 0, 0);
        // one barrier: frees buffer `cur` for overwrite AND (via the compiler's
        // vmcnt(0) drain) guarantees chunk it+1 is resident for the next iter.
        __syncthreads();
    }

    // C/D layout: col = lane&15, row = (lane>>4)*4 + reg
    if (EPI == 0) {
#pragma unroll
        for (int rt = 0; rt < 4; ++rt) {
#pragma unroll
            for (int reg = 0; reg < 4; ++reg) {
                float v = 0.f;
#pragma unroll
                for (int ct = 0; ct < 4; ++ct) v += __expf(acc[rt][ct][reg] * INV_T);
                v += __shfl_xor(v, 1);
                v += __shfl_xor(v, 2);
                v += __shfl_xor(v, 4);
                v += __shfl_xor(v, 8);
                if (lr == 0) {
                    int row = m0 + wm * 64 + rt * 16 + q * 4 + reg;
                    atomicAdd(&S[row], v);
                }
            }
        }
    } else {
        float lsum = 0.f;
#pragma unroll
        for (int rt = 0; rt < 4; ++rt) {
#pragma unroll
            for (int reg = 0; reg < 4; ++reg) {
                int row = m0 + wm * 64 + rt * 16 + q * 4 + reg;
                float Sv = S[row];
#pragma unroll
                for (int ct = 0; ct < 4; ++ct) {
                    float pe = __expf(acc[rt][ct][reg] * INV_T);
                    lsum -= __logf(pe / (pe + Sv) + EPS_L);
                }
            }
        }
#pragma unroll
        for (int off = 1; off < 64; off <<= 1) lsum += __shfl_xor(lsum, off);
        if (lane == 0) atomicAdd(loss_sum, lsum);
    }
}

// ---- finalize: dot the (strided) column sums, emit the 4 scalars ----
__global__ void finalize_k(const float* __restrict__ csA, const float* __restrict__ csP,
                           const float* __restrict__ csN, const float* __restrict__ lsum,
                           float* __restrict__ out) {
    int tid = threadIdx.x;  // 512
    float av = csA[(size_t)tid * CS_STRIDE];
    float dp = av * csP[(size_t)tid * CS_STRIDE];
    float dn = av * csN[(size_t)tid * CS_STRIDE];
#pragma unroll
    for (int off = 1; off < 64; off <<= 1) {
        dp += __shfl_xor(dp, off);
        dn += __shfl_xor(dn, off);
    }
    __shared__ float red[16];
    int wid = tid >> 6, lane = tid & 63;
    if (lane == 0) { red[wid] = dp; red[8 + wid] = dn; }
    __syncthreads();
    if (tid == 0) {
        float sdp = 0.f, sdn = 0.f;
#pragma unroll
        for (int i = 0; i < 8; ++i) { sdp += red[i]; sdn += red[8 + i]; }
        float mean_pos = sdp * INV_T / ((float)B_ROWS * (float)P_ROWS);
        float mean_neg = sdn * INV_T / ((float)B_ROWS * (float)N_ROWS);
        out[0] = lsum[0] / ((float)B_ROWS * (float)P_ROWS);
        out[1] = mean_pos;
        out[2] = mean_neg;
        out[3] = mean_pos - mean_neg;
    }
}

extern "C" void kernel_launch(void* const* d_in, const int* in_sizes, int n_in,
                              void* d_out, int out_size, void* d_ws, size_t ws_size,
                              hipStream_t stream) {
    const float* anc = (const float*)d_in[0];
    const float* pos = (const float*)d_in[1];
    const float* neg = (const float*)d_in[2];
    float* out = (float*)d_out;

    fp8_t* a8 = (fp8_t*)d_ws;
    fp8_t* p8 = a8 + (size_t)B_ROWS * D_DIM;
    fp8_t* n8 = p8 + (size_t)P_ROWS * D_DIM;
    float* fsec = (float*)(n8 + (size_t)N_ROWS * D_DIM);
    float* S    = fsec;
    float* csA  = S + B_ROWS;
    float* csP  = csA + D_DIM * CS_STRIDE;
    float* csN  = csP + D_DIM * CS_STRIDE;
    float* lsum = csN + D_DIM * CS_STRIDE;

    hipMemsetAsync(fsec, 0, (B_ROWS + 3 * D_DIM * CS_STRIDE + 1) * sizeof(float), stream);

    norm_colsum<<<1024, 256, 0, stream>>>(anc, pos, neg, a8, p8, n8, csA, csP, csN);

    gemm_epi<0><<<dim3(N_ROWS / BN, B_ROWS / BM), 256, 0, stream>>>(a8, n8, S, nullptr);
    gemm_epi<1><<<dim3(P_ROWS / BN, B_ROWS / BM), 256, 0, stream>>>(a8, p8, S, lsum);

    finalize_k<<<1, 512, 0, stream>>>(csA, csP, csN, lsum, out);
}